// Round 8
// baseline (868.341 us; speedup 1.0000x reference)
//
#include <hip/hip_runtime.h>

// ============================================================================
// R10: zero-LDS-atomic pipeline.
// R3-R9 law: 38.4M LDS atomic lane-ops <=> ~222us regardless of occupancy,
// MLP, operand locality, or bank conflicts (R9: conflicts 4.38M->175K, time
// unchanged) => ~3.55 cy per atomic lane-op per CU, a hard atomic-pipe limit.
// R10 removes every atomic: count/place use wave-vote arbitration (lockstep
// wave64, shared vote slot, winner does exclusive plain LDS RMW); accum gives
// each thread an exclusive color class (owner&127) and substrip-private force
// slabs (4x37.5KB) so force accumulation is plain read-add-write.
// ============================================================================

#define NBIN   32
#define BA     3200                  // atoms per bin; 32*3200 = 102400
#define NCLS   128                   // color classes (owner & 127)
#define LBK    (NBIN * NCLS)         // 4096 local buckets per wave-segment
#define NSEG   512                   // wave-segments
#define CBLK   64                    // count/place blocks (8 waves each)
#define NB_TOT (NSEG * LBK)          // 2,097,152 buckets
#define NROW   8                     // force rows (strips)
#define ROW_F  307200                // floats per row = NBIN * BA * 3

// ---------------- fallback path (R3, proven 313us) ----------------
#define NBINS      8
#define BIN_ATOMS  12800
#define BIN_F      (BIN_ATOMS * 3)
#define BLOCK      1024
#define MAXCHUNKS  32

__device__ __forceinline__ unsigned nt_load_u(const unsigned* p) {
    return __builtin_nontemporal_load(p);
}

// ---- vote-arbitrated exclusive bucket op (no atomics) ----------------------
// All lanes with the same bucket collide on one vote slot; the lane whose id
// is visible after the store wins and performs an exclusive plain RMW; losers
// retry. Cross-wave interference on the shared vote array only causes extra
// retries (cursor/hist arrays are wave-private). Serial fallback bounds it.

__device__ __forceinline__ void vote_count(volatile unsigned* vh,
                                           volatile unsigned* vote,
                                           int lane, int act, unsigned lb) {
    int pend = act, guard = 0;
    while (__any(pend)) {
        if (pend) vote[lb & 1023u] = (unsigned)lane;
        if (pend && vote[lb & 1023u] == (unsigned)lane) { vh[lb] += 1u; pend = 0; }
        if (++guard >= 72) break;
    }
    if (__any(pend)) {
        for (int l2 = 0; l2 < 64; ++l2)
            if (pend && lane == l2) { vh[lb] += 1u; pend = 0; }
    }
}

__device__ __forceinline__ void vote_place(volatile unsigned* vc,
                                           volatile unsigned* vote,
                                           unsigned* __restrict__ recs,
                                           int lane, int act, unsigned lb,
                                           unsigned enc) {
    int pend = act, guard = 0;
    while (__any(pend)) {
        if (pend) vote[lb & 1023u] = (unsigned)lane;
        if (pend && vote[lb & 1023u] == (unsigned)lane) {
            const unsigned s = vc[lb]; vc[lb] = s + 1u;
            recs[s] = enc;
            pend = 0;
        }
        if (++guard >= 72) break;
    }
    if (__any(pend)) {
        for (int l2 = 0; l2 < 64; ++l2)
            if (pend && lane == l2) {
                const unsigned s = vc[lb]; vc[lb] = s + 1u;
                recs[s] = enc;
                pend = 0;
            }
    }
}

// ---------------------------------------------------------------------------
// K1: count records per (wave-segment, bin, color) + build pos4.
// LDS: 8 wave-private histograms (4096 ea) + shared 1024 vote = 135,168 B.
// ---------------------------------------------------------------------------
__global__ __launch_bounds__(512) void pf_count(
    const float* __restrict__ pos, float4* __restrict__ pos4,
    const int* __restrict__ src, const int* __restrict__ dst,
    unsigned* __restrict__ cnt, int nEdges, int nAtoms)
{
    extern __shared__ unsigned u[];          // [8*4096 hist | 1024 vote]
    const int t = threadIdx.x, lane = t & 63, wv = t >> 6;
    const int bid = (int)blockIdx.x;

    for (int k = t; k < 8 * LBK + 1024; k += 512) u[k] = 0u;
    for (int i = bid * 512 + t; i < nAtoms; i += CBLK * 512)
        pos4[i] = make_float4(pos[3 * i + 0], pos[3 * i + 1], pos[3 * i + 2], 0.f);
    __syncthreads();

    volatile unsigned* vh   = u + (size_t)wv * LBK;
    volatile unsigned* vote = u + 8 * LBK;

    const int w    = bid * 8 + wv;
    const int epw  = (nEdges + NSEG - 1) / NSEG;
    const int ebeg = w * epw;
    const int eend = (ebeg + epw < nEdges) ? (ebeg + epw) : nEdges;

    for (int base = ebeg; base < eend; base += 64) {
        const int e = base + lane;
        const int act = e < eend;
        unsigned su = 0, du = 0;
        if (act) { su = (unsigned)src[e]; du = (unsigned)dst[e]; }
        // src-owner record
        {
            const unsigned bin = su / BA;
            vote_count(vh, vote, lane, act, bin * NCLS + (su & (NCLS - 1u)));
        }
        // dst-owner record
        {
            const unsigned bin = du / BA;
            vote_count(vh, vote, lane, act, bin * NCLS + (du & (NCLS - 1u)));
        }
    }
    __syncthreads();
    for (int k = lane; k < LBK; k += 64)
        cnt[(size_t)w * LBK + k] = u[(size_t)wv * LBK + k];
}

// ---------------------------------------------------------------------------
// K2a/b/c: parallel exclusive scan over NB_TOT bucket counts.
// ---------------------------------------------------------------------------
__global__ __launch_bounds__(1024) void pf_scanA(
    const unsigned* __restrict__ cnt, unsigned* __restrict__ bstart,
    unsigned* __restrict__ btot)
{
    __shared__ unsigned wt[16], wo[16];
    const int t = threadIdx.x, lane = t & 63, wv = t >> 6;
    const int gid = (int)blockIdx.x * 1024 + t;
    const unsigned v = cnt[gid];
    unsigned x = v;
    #pragma unroll
    for (int off = 1; off < 64; off <<= 1) {
        const unsigned n = __shfl_up(x, off, 64);
        if (lane >= off) x += n;
    }
    if (lane == 63) wt[wv] = x;
    __syncthreads();
    if (t == 0) {
        unsigned run = 0;
        #pragma unroll
        for (int w = 0; w < 16; ++w) { wo[w] = run; run += wt[w]; }
        btot[blockIdx.x] = run;
    }
    __syncthreads();
    bstart[gid] = (x - v) + wo[wv];
}

__global__ __launch_bounds__(1024) void pf_scanB(
    const unsigned* __restrict__ btot, unsigned* __restrict__ boffs)
{
    __shared__ unsigned wt[16], wo[16];
    const int t = threadIdx.x, lane = t & 63, wv = t >> 6;
    const unsigned a = btot[2 * t];
    const unsigned b = btot[2 * t + 1];
    const unsigned p = a + b;
    unsigned x = p;
    #pragma unroll
    for (int off = 1; off < 64; off <<= 1) {
        const unsigned n = __shfl_up(x, off, 64);
        if (lane >= off) x += n;
    }
    if (lane == 63) wt[wv] = x;
    __syncthreads();
    if (t == 0) {
        unsigned run = 0;
        #pragma unroll
        for (int w = 0; w < 16; ++w) { wo[w] = run; run += wt[w]; }
    }
    __syncthreads();
    const unsigned ex = (x - p) + wo[wv];
    boffs[2 * t] = ex;
    boffs[2 * t + 1] = ex + a;
}

__global__ __launch_bounds__(1024) void pf_scanC(
    unsigned* __restrict__ bstart, const unsigned* __restrict__ boffs, int nRec)
{
    const int gid = (int)blockIdx.x * 1024 + threadIdx.x;
    bstart[gid] += boffs[blockIdx.x];
    if (gid == 0) bstart[NB_TOT] = (unsigned)nRec;
}

// ---------------------------------------------------------------------------
// K3: place records. rec = li(12b)<<18 | eflag<<17 | other(17b).
// LDS: 8 wave-private cursor arrays (init from bstart) + vote = 135,168 B.
// ---------------------------------------------------------------------------
__global__ __launch_bounds__(512) void pf_place(
    const int* __restrict__ src, const int* __restrict__ dst,
    const unsigned* __restrict__ bstart, unsigned* __restrict__ recs, int nEdges)
{
    extern __shared__ unsigned u[];          // [8*4096 cursors | 1024 vote]
    const int t = threadIdx.x, lane = t & 63, wv = t >> 6;
    const int bid = (int)blockIdx.x;
    const int w = bid * 8 + wv;

    for (int k = lane; k < LBK; k += 64)
        u[(size_t)wv * LBK + k] = bstart[(size_t)w * LBK + k];
    __syncthreads();

    volatile unsigned* vc   = u + (size_t)wv * LBK;
    volatile unsigned* vote = u + 8 * LBK;

    const int epw  = (nEdges + NSEG - 1) / NSEG;
    const int ebeg = w * epw;
    const int eend = (ebeg + epw < nEdges) ? (ebeg + epw) : nEdges;

    for (int base = ebeg; base < eend; base += 64) {
        const int e = base + lane;
        const int act = e < eend;
        unsigned su = 0, du = 0;
        if (act) { su = (unsigned)src[e]; du = (unsigned)dst[e]; }
        {   // src-owner record (carries the energy flag)
            const unsigned bin = su / BA;
            const unsigned li  = su - bin * BA;
            vote_place(vc, vote, recs, lane, act,
                       bin * NCLS + (su & (NCLS - 1u)),
                       (li << 18) | (1u << 17) | du);
        }
        {   // dst-owner record
            const unsigned bin = du / BA;
            const unsigned li  = du - bin * BA;
            vote_place(vc, vote, recs, lane, act,
                       bin * NCLS + (du & (NCLS - 1u)),
                       (li << 18) | su);
        }
    }
}

// ---------------------------------------------------------------------------
// K4: accumulation, zero atomics. Block = (bin, strip): 32x8 = 256 blocks.
// Thread (ss = t>>7, c = t&127) exclusively owns color class c in substrip
// ss; 4 substrip-private force slabs (4 x 9600 f32 = 150 KiB) make the force
// add a plain read-add-write. Slabs merged at flush into row `strip`.
// ---------------------------------------------------------------------------
__global__ __launch_bounds__(512) void pf_accum(
    const float4* __restrict__ pos4,
    const float* __restrict__ sigma_p, const float* __restrict__ eps_p,
    const unsigned* __restrict__ recs, const unsigned* __restrict__ bstart,
    float* __restrict__ frep,            // [NROW][ROW_F]
    float* __restrict__ erep)            // [256]
{
    extern __shared__ float sh[];        // 4 slabs x 9600 floats
    __shared__ float sE[8];
    const int t = threadIdx.x, lane = t & 63, wv = t >> 6;
    const int b = (int)blockIdx.x;
    const int bin = b & 31, strip = b >> 5;
    const int c = t & (NCLS - 1), ss = t >> 7;

    for (int k = t; k < 4 * 9600 / 4; k += 512)
        ((float4*)sh)[k] = make_float4(0.f, 0.f, 0.f, 0.f);
    __syncthreads();

    const float sigma = sigma_p[0], eps = eps_p[0];
    const float sig2 = sigma * sigma;
    const float c12 = 12.f * eps, c4 = 4.f * eps;

    float* sF = sh + ss * 9600;
    const int binBase = bin * BA;
    float ev = 0.f;

    for (int k = 0; k < 16; ++k) {
        const int seg = strip * 64 + ss * 16 + k;
        const size_t g = (size_t)seg * LBK + bin * NCLS + c;
        const int beg = (int)bstart[g];
        const int end = (int)bstart[g + 1];
        for (int r = beg; r < end; ++r) {
            const unsigned rec = nt_load_u(recs + r);
            const int li = rec >> 18;
            const int o  = rec & 0x1FFFF;
            const float4 pa = pos4[binBase + li];
            const float4 po = pos4[o];
            const float dx = pa.x - po.x, dy = pa.y - po.y, dz = pa.z - po.z;
            const float r2   = dx * dx + dy * dy + dz * dz;
            const float ir2  = 1.0f / r2;
            const float s2   = sig2 * ir2;
            const float sr6  = s2 * s2 * s2;
            const float sr12 = sr6 * sr6;
            const float fs   = c12 * (2.f * sr12 - sr6) * ir2;
            sF[3 * li + 0] += fs * dx;       // plain RMW: (ss,c)-exclusive
            sF[3 * li + 1] += fs * dy;
            sF[3 * li + 2] += fs * dz;
            ev += (rec & (1u << 17)) ? c4 * (sr12 - sr6) : 0.f;
        }
    }

    #pragma unroll
    for (int off = 32; off > 0; off >>= 1) ev += __shfl_down(ev, off, 64);
    if (lane == 0) sE[wv] = ev;
    __syncthreads();

    // merge 4 slabs -> row `strip`, bin segment
    float4* dOut = (float4*)(frep + (size_t)strip * ROW_F + (size_t)bin * (BA * 3));
    const float4* s0 = (const float4*)(sh);
    const float4* s1 = (const float4*)(sh + 9600);
    const float4* s2 = (const float4*)(sh + 19200);
    const float4* s3 = (const float4*)(sh + 28800);
    for (int k = t; k < 9600 / 4; k += 512) {
        const float4 a = s0[k], b2 = s1[k], c2 = s2[k], d2 = s3[k];
        dOut[k] = make_float4(a.x + b2.x + c2.x + d2.x, a.y + b2.y + c2.y + d2.y,
                              a.z + b2.z + c2.z + d2.z, a.w + b2.w + c2.w + d2.w);
    }
    if (t == 0) {
        float e = 0.f;
        #pragma unroll
        for (int w = 0; w < 8; ++w) e += sE[w];
        erep[b] = e;
    }
}

// ---------------------------------------------------------------------------
// Reduce (rows -> output).
// ---------------------------------------------------------------------------
__global__ __launch_bounds__(256) void pairforce_reduce(
    const float* __restrict__ frep,
    const float* __restrict__ erep,
    float* __restrict__ out, int n3, int nChunks, int nPart)
{
    const int i = blockIdx.x * 256 + threadIdx.x;
    if (i < n3) {
        float acc = 0.f;
        for (int c = 0; c < nChunks; ++c)
            acc += frep[(size_t)c * ROW_F + i];
        out[1 + i] = acc;
    }
    if (blockIdx.x == gridDim.x - 1) {
        float e = 0.f;
        for (int jj = threadIdx.x; jj < nPart; jj += 256) e += erep[jj];
        #pragma unroll
        for (int off = 32; off > 0; off >>= 1) e += __shfl_down(e, off, 64);
        __shared__ float ep[4];
        if ((threadIdx.x & 63) == 0) ep[threadIdx.x >> 6] = e;
        __syncthreads();
        if (threadIdx.x == 0) out[0] = ep[0] + ep[1] + ep[2] + ep[3];
    }
}

// ---------------------------------------------------------------------------
// Fallback: R3's binned kernel, verbatim.
// ---------------------------------------------------------------------------
__global__ __launch_bounds__(BLOCK, 1) void pairforce_binned(
    const float* __restrict__ pos,
    const float* __restrict__ sigma_p,
    const float* __restrict__ eps_p,
    const int*   __restrict__ src,
    const int*   __restrict__ dst,
    float* __restrict__ frep,
    float* __restrict__ erep,
    int nEdges, int chunkEdges)
{
    extern __shared__ float sh[];
    const int t = threadIdx.x;
    const int b = blockIdx.x % NBINS;
    const int c = blockIdx.x / NBINS;

    for (int jj = t; jj < (BIN_F + 16) / 4; jj += BLOCK)
        ((float4*)sh)[jj] = make_float4(0.f, 0.f, 0.f, 0.f);
    __syncthreads();

    const float sigma = sigma_p[0];
    const float eps   = eps_p[0];
    const float sig2  = sigma * sigma;
    const int binStart = b * BIN_ATOMS;

    const int start = c * chunkEdges;
    const int end   = min(start + chunkEdges, nEdges);

    const int4* src4 = (const int4*)src;
    const int4* dst4 = (const int4*)dst;

    float ev = 0.0f;

    for (int i4 = (start >> 2) + t; i4 < (end >> 2); i4 += BLOCK) {
        const int4 s4 = src4[i4];
        const int4 d4 = dst4[i4];
        #pragma unroll
        for (int k = 0; k < 4; ++k) {
            const int s = (k == 0) ? s4.x : (k == 1) ? s4.y : (k == 2) ? s4.z : s4.w;
            const int d = (k == 0) ? d4.x : (k == 1) ? d4.y : (k == 2) ? d4.z : d4.w;
            const unsigned ls = (unsigned)(s - binStart);
            const unsigned ld = (unsigned)(d - binStart);
            const bool hs = ls < BIN_ATOMS;
            const bool hd = ld < BIN_ATOMS;
            if (hs | hd) {
                const float dx = pos[3 * s + 0] - pos[3 * d + 0];
                const float dy = pos[3 * s + 1] - pos[3 * d + 1];
                const float dz = pos[3 * s + 2] - pos[3 * d + 2];
                const float r2     = dx * dx + dy * dy + dz * dz;
                const float inv_r2 = 1.0f / r2;
                const float s2     = sig2 * inv_r2;
                const float sr6    = s2 * s2 * s2;
                const float sr12   = sr6 * sr6;
                const float fs = 12.0f * eps * (2.0f * sr12 - sr6) * inv_r2;
                const float fx = fs * dx;
                const float fy = fs * dy;
                const float fz = fs * dz;
                if (hs) {
                    atomicAdd(&sh[3 * ls + 0],  fx);
                    atomicAdd(&sh[3 * ls + 1],  fy);
                    atomicAdd(&sh[3 * ls + 2],  fz);
                    ev += 4.0f * eps * (sr12 - sr6);
                }
                if (hd) {
                    atomicAdd(&sh[3 * ld + 0], -fx);
                    atomicAdd(&sh[3 * ld + 1], -fy);
                    atomicAdd(&sh[3 * ld + 2], -fz);
                }
            }
        }
    }

    #pragma unroll
    for (int off = 32; off > 0; off >>= 1)
        ev += __shfl_down(ev, off, 64);
    if ((t & 63) == 0) sh[BIN_F + (t >> 6)] = ev;
    __syncthreads();

    float4* outSeg = (float4*)(frep + (size_t)c * ROW_F + (size_t)b * BIN_F);
    for (int jj = t; jj < BIN_F / 4; jj += BLOCK)
        outSeg[jj] = ((float4*)sh)[jj];

    if (t == 0) {
        float e = 0.f;
        #pragma unroll
        for (int w = 0; w < 16; ++w) e += sh[BIN_F + w];
        erep[blockIdx.x] = e;
    }
}

extern "C" void kernel_launch(void* const* d_in, const int* in_sizes, int n_in,
                              void* d_out, int out_size, void* d_ws, size_t ws_size,
                              hipStream_t stream)
{
    const float* pos     = (const float*)d_in[0];
    const float* sigma_p = (const float*)d_in[1];
    const float* eps_p   = (const float*)d_in[2];
    const int*   edge    = (const int*)d_in[3];

    const int nEdges = in_sizes[3] / 2;      // edge_index is [2, E]
    const int* src = edge;
    const int* dst = edge + nEdges;

    const int n3 = out_size - 1;             // 3*N
    const int nAtoms = n3 / 3;
    const int nRec = 2 * nEdges;

    // ---- workspace (~79.5 MB; >=88.5 MB proven available) ----
    auto alignup = [](size_t x) { return (x + 255) & ~(size_t)255; };
    size_t off = 0;
    unsigned* recs   = (unsigned*)((char*)d_ws + off); off = alignup(off + (size_t)nRec * 4);
    unsigned* cntp   = (unsigned*)((char*)d_ws + off); off = alignup(off + (size_t)NB_TOT * 4);
    unsigned* bstart = (unsigned*)((char*)d_ws + off); off = alignup(off + (size_t)(NB_TOT + 1) * 4);
    unsigned* btot   = (unsigned*)((char*)d_ws + off); off = alignup(off + 2048 * 4);
    unsigned* boffs  = (unsigned*)((char*)d_ws + off); off = alignup(off + 2048 * 4);
    float*    pos4   = (float*)((char*)d_ws + off);    off = alignup(off + (size_t)(NBIN * BA) * 16);
    float*    frepN  = (float*)((char*)d_ws + off);    off = alignup(off + (size_t)NROW * ROW_F * 4);
    float*    erepN  = (float*)((char*)d_ws + off);    off = alignup(off + 256 * 4);

    if (ws_size >= off && nAtoms <= NBIN * BA && nEdges > 0 && (nEdges & 3) == 0) {
        const size_t shCP = (size_t)(8 * LBK + 1024) * 4;        // 135,168 B
        pf_count<<<CBLK, 512, shCP, stream>>>(pos, (float4*)pos4, src, dst,
                                              cntp, nEdges, nAtoms);
        pf_scanA<<<NB_TOT / 1024, 1024, 0, stream>>>(cntp, bstart, btot);
        pf_scanB<<<1, 1024, 0, stream>>>(btot, boffs);
        pf_scanC<<<NB_TOT / 1024, 1024, 0, stream>>>(bstart, boffs, nRec);
        pf_place<<<CBLK, 512, shCP, stream>>>(src, dst, bstart, recs, nEdges);
        const size_t shA = (size_t)(4 * 9600) * 4;               // 153,600 B
        pf_accum<<<NBIN * NROW, 512, shA, stream>>>((const float4*)pos4,
                                                    sigma_p, eps_p, recs, bstart,
                                                    frepN, erepN);
        pairforce_reduce<<<(n3 + 255) / 256, 256, 0, stream>>>(
            frepN, erepN, (float*)d_out, n3, NROW, NBIN * NROW);
        return;
    }

    // ---- fallback: R3 path ----
    const size_t rowBytes = (size_t)ROW_F * sizeof(float);
    int nChunks = (int)((ws_size - 4096) / rowBytes);
    if (nChunks > MAXCHUNKS) nChunks = MAXCHUNKS;
    if (nChunks < 1) nChunks = 1;

    const int chunkEdges = (((nEdges + nChunks - 1) / nChunks) + 3) & ~3;

    float* frep = (float*)d_ws;
    float* erep = frep + (size_t)nChunks * ROW_F;

    const size_t shbytes = (size_t)(BIN_F + 16) * sizeof(float);

    const int grid1 = nChunks * NBINS;
    pairforce_binned<<<grid1, BLOCK, shbytes, stream>>>(
        pos, sigma_p, eps_p, src, dst, frep, erep, nEdges, chunkEdges);

    const int grid2 = (n3 + 255) / 256;
    pairforce_reduce<<<grid2, 256, 0, stream>>>(
        frep, erep, (float*)d_out, n3, nChunks, nChunks * NBINS);
}